// Round 13
// baseline (422.641 us; speedup 1.0000x reference)
//
#include <hip/hip_runtime.h>
#include <hip/hip_cooperative_groups.h>

namespace cg = cooperative_groups;

#define NN 50000
#define NE 800000
#define DF 128
#define BM 32
#define NB ((NN + BM - 1) / BM)   // 1563
#define SCAN_B ((NN + 255) / 256) // 196
#define GB ((NN + 63) / 64)       // 782 gemm blocks
#define HB ((NE + 255) / 256)     // 3125 hist blocks
#define COOP_B 1024               // cooperative grid (co-resident on 256 CUs)

typedef __attribute__((ext_vector_type(8))) short bf16x8;
typedef __attribute__((ext_vector_type(4))) float f32x4;
typedef __attribute__((ext_vector_type(2))) float f32x2;

// ---- workspace layout (bytes) ----
static const size_t OFF_DEG  = 0;         // u32[NN]
static const size_t OFF_OFFS = 204800;    // u32[NN+1]
static const size_t OFF_PART = 409600;    // u32[SCAN_B]
static const size_t OFF_RANK = 614400;    // u32[NE]
static const size_t OFF_CSR  = 3814400;   // int2[NE]
static const size_t OFF_BCTA = 10214400;  // bf16[128][256]: [col][k], k<128=W1, k>=128=We
static const size_t OFF_W2T  = 10279936;  // bf16[128][128]: [col][k] = W[k][128+col]
static const size_t OFF_P2   = 10312704;  // bf16[NN][128] = bf16(X@W[:,128:])
// total ~23.1 MB

__device__ __forceinline__ unsigned f2bf(float f) {
    unsigned u = __float_as_uint(f);
    return (u + 0x7FFFu + ((u >> 16) & 1u)) >> 16;
}
// non-temporal: EF rows are touched exactly once -> keep the 410MB stream
// from evicting the P2 gather table.
__device__ __forceinline__ f32x2 ntload2(const float* p) {
    return __builtin_nontemporal_load(reinterpret_cast<const f32x2*>(p));
}

// 32B csr block (4 edges), 8B-aligned; wave-uniform address -> scalar block load
struct __attribute__((aligned(8))) CsrBlk { int2 e[4]; };

// zero deg + build BcTa (concat [W1; We] transposed) + W2T
__global__ void k_setup(const float* __restrict__ W, const float* __restrict__ We,
                        unsigned* __restrict__ deg, unsigned short* __restrict__ BcTa,
                        unsigned short* __restrict__ W2T) {
    int idx = blockIdx.x * blockDim.x + threadIdx.x;
    if (idx < NN) deg[idx] = 0;
    if (idx < 128 * 256) {
        int col = idx >> 8, k = idx & 255;
        float v = (k < 128) ? W[k * 256 + col] : We[(k - 128) * 128 + col];
        BcTa[idx] = (unsigned short)f2bf(v);
    }
    if (idx < 128 * 128) {
        int col = idx >> 7, k = idx & 127;
        W2T[idx] = (unsigned short)f2bf(W[k * 256 + 128 + col]);
    }
}

// blocks [0,GB): P2 = bf16(X@W[:,128:]); blocks [GB,GB+HB): degree hist + rank
__global__ __launch_bounds__(256) void k_gemm1hist(
    const float* __restrict__ X, const unsigned short* __restrict__ W2T,
    unsigned short* __restrict__ P2, const int* __restrict__ rcv,
    unsigned* __restrict__ deg, unsigned* __restrict__ rank) {
    __shared__ unsigned short As[64 * 128];  // 16 KiB, XOR-swizzled
    if (blockIdx.x >= GB) {
        int e = (blockIdx.x - GB) * 256 + threadIdx.x;
        if (e < NE) rank[e] = atomicAdd(&deg[rcv[e]], 1u);
        return;
    }
    const int tid = threadIdx.x;
    const int w = tid >> 6, lane = tid & 63;
    const int l15 = lane & 15, l4 = lane >> 4;
    const int m0 = blockIdx.x * 64;
    char* Asb = (char*)As;

    for (int i = tid; i < 64 * 32; i += 256) {
        int r = i >> 5, g = i & 31;
        int n = m0 + r;
        f32x4 v = {0.f, 0.f, 0.f, 0.f};
        if (n < NN) v = *reinterpret_cast<const f32x4*>(X + (size_t)n * DF + g * 4);
        unsigned pk0 = f2bf(v[0]) | (f2bf(v[1]) << 16);
        unsigned pk1 = f2bf(v[2]) | (f2bf(v[3]) << 16);
        unsigned byte = (unsigned)(r * 256 + g * 8) ^ ((unsigned)(r & 7) << 4);
        *reinterpret_cast<uint2*>(Asb + byte) = make_uint2(pk0, pk1);
    }
    __syncthreads();

    const int rrow = w * 16 + l15;
    const unsigned rswz = (unsigned)(rrow & 7) << 4;
    f32x4 acc[8];
#pragma unroll
    for (int ng = 0; ng < 8; ++ng) acc[ng] = (f32x4){0.f, 0.f, 0.f, 0.f};
#pragma unroll
    for (int kk = 0; kk < 4; ++kk) {
        unsigned abyte = (unsigned)(rrow * 256 + (kk * 32 + l4 * 8) * 2) ^ rswz;
        bf16x8 a = *reinterpret_cast<const bf16x8*>(Asb + abyte);
#pragma unroll
        for (int ng = 0; ng < 8; ++ng) {
            bf16x8 b = *reinterpret_cast<const bf16x8*>(
                W2T + (size_t)(ng * 16 + l15) * 128 + kk * 32 + l4 * 8);
            acc[ng] = __builtin_amdgcn_mfma_f32_16x16x32_bf16(a, b, acc[ng], 0, 0, 0);
        }
    }
#pragma unroll
    for (int ng = 0; ng < 8; ++ng) {
        int col = ng * 16 + l15;
#pragma unroll
        for (int j = 0; j < 4; ++j) {
            int row = m0 + w * 16 + l4 * 4 + j;
            if (row < NN) P2[(size_t)row * DF + col] = (unsigned short)f2bf(acc[ng][j]);
        }
    }
}

// cooperative: scan1 -> grid.sync -> scan3 -> grid.sync -> scatter
__global__ __launch_bounds__(256) void k_csr(
    const unsigned* __restrict__ deg, unsigned* __restrict__ part,
    unsigned* __restrict__ offs, const int* __restrict__ snd,
    const int* __restrict__ rcv, const unsigned* __restrict__ rank,
    int2* __restrict__ csr) {
    cg::grid_group grid = cg::this_grid();
    const int b = blockIdx.x;
    const int tid = threadIdx.x;
    const int w = tid >> 6, lane = tid & 63;

    // ---- phase 1: per-chunk sums (blocks 0..SCAN_B-1) ----
    if (b < SCAN_B) {
        int idx = b * 256 + tid;
        unsigned v = (idx < NN) ? deg[idx] : 0;
#pragma unroll
        for (int o = 32; o; o >>= 1) v += __shfl_down(v, o);
        __shared__ unsigned wsum1[4];
        if (lane == 0) wsum1[w] = v;
        __syncthreads();
        if (tid == 0) part[b] = wsum1[0] + wsum1[1] + wsum1[2] + wsum1[3];
    }
    grid.sync();

    // ---- phase 2: exclusive scan (base from part[]) ----
    if (b < SCAN_B) {
        int idx = b * 256 + tid;
        unsigned v = (idx < NN) ? deg[idx] : 0;
        unsigned x = v;
#pragma unroll
        for (int o = 1; o < 64; o <<= 1) {
            unsigned y = __shfl_up(x, o);
            if (lane >= o) x += y;
        }
        __shared__ unsigned wsum[4];
        __shared__ unsigned base_s;
        if (lane == 63) wsum[w] = x;
        if (w == 0) {
            unsigned s = 0;
            for (int i = lane; i < b; i += 64) s += part[i];
#pragma unroll
            for (int o = 32; o; o >>= 1) s += __shfl_down(s, o);
            if (lane == 0) base_s = s;
        }
        __syncthreads();
        unsigned base = base_s;
        for (int i = 0; i < w; ++i) base += wsum[i];
        if (idx < NN) offs[idx] = base + x - v;
        if (b == SCAN_B - 1 && tid == 255) offs[NN] = base + x;
    }
    grid.sync();

    // ---- phase 3: scatter (grid-stride over edges) ----
    for (int e = b * 256 + tid; e < NE; e += COOP_B * 256)
        csr[offs[rcv[e]] + rank[e]] = make_int2(snd[e], e);
}

// fused: per 32-node tile, stage X (bf16) into A-tile cols 0..127, aggregate
// EF->Ae (A-tile cols 128..255) and P2->XJ, then one K=256 MFMA pass:
// out = [X|Ae]@[W1;We] + XJ + biases.
// phase A: whole wave per edge; csr read as 32B uniform blocks (scalar dwordx8);
// masked edges redirected to the body's first (always-valid) entry.
__global__ __launch_bounds__(512) void k_aggemm(
    const float* __restrict__ X, const float* __restrict__ EF,
    const unsigned short* __restrict__ P2, const unsigned* __restrict__ offs,
    const int2* __restrict__ csr, const unsigned short* __restrict__ BcTa,
    const float* __restrict__ bW, const float* __restrict__ bWe,
    float* __restrict__ out) {
    __shared__ unsigned short As[BM * 256];  // 16 KiB [32][256], XOR-swizzled
    __shared__ float XJ[BM][132];            // padded stride: conflict-free epilogue
    __shared__ float cf_s[BM];
    const int tid = threadIdx.x;
    const int w = tid >> 6, lane = tid & 63;
    const int m0 = blockIdx.x * BM;
    char* Asb = (char*)As;

    // ---- phase B first (independent bulk loads prefetch under phase A) ----
    for (int i = tid; i < BM * 32; i += 512) {
        int r = i >> 5, g = i & 31;
        int n = m0 + r;
        f32x4 v = {0.f, 0.f, 0.f, 0.f};
        if (n < NN) v = *reinterpret_cast<const f32x4*>(X + (size_t)n * DF + g * 4);
        unsigned pk0 = f2bf(v[0]) | (f2bf(v[1]) << 16);
        unsigned pk1 = f2bf(v[2]) | (f2bf(v[3]) << 16);
        unsigned byte = (unsigned)(r * 512 + g * 8) ^ ((unsigned)(r & 7) << 4);
        *reinterpret_cast<uint2*>(Asb + byte) = make_uint2(pk0, pk1);
    }

    // ---- phase A: wave owns 4 nodes; whole wave per edge ----
    {
        const int l2 = lane * 2;
        for (int t = 0; t < 4; ++t) {
            int r = w * 4 + t;
            int n = m0 + r;
            unsigned s0 = 0, s1 = 0;
            if (n < NN) { s0 = offs[n]; s1 = offs[n + 1]; }
            s0 = __builtin_amdgcn_readfirstlane(s0);
            s1 = __builtin_amdgcn_readfirstlane(s1);
            unsigned dg = s1 - s0;
            float efa = 0.f, efb = 0.f, xja = 0.f, xjb = 0.f;
            unsigned nb = (dg + 7) >> 3;  // 8-edge bodies, masked tail
            unsigned p = s0;
            for (unsigned bdy = 0; bdy < nb; ++bdy, p += 8) {
                // uniform 32B block loads (over-read past s1 stays inside ws;
                // masked entries are value-redirected below)
                CsrBlk bA = *reinterpret_cast<const CsrBlk*>(csr + p);
                CsrBlk bB = *reinterpret_cast<const CsrBlk*>(csr + p + 4);
                int2 safe = bA.e[0];  // p < s1 always holds for body start
#pragma unroll
                for (int i = 0; i < 8; ++i) {
                    bool act = p + i < s1;
                    int2 se = (i < 4) ? bA.e[i] : bB.e[i - 4];
                    se = act ? se : safe;  // uniform cselect
                    f32x2 ev = ntload2(EF + (size_t)se.y * DF + l2);
                    unsigned pu = *reinterpret_cast<const unsigned*>(
                        P2 + (size_t)se.x * DF + l2);
                    float m = act ? 1.f : 0.f;
                    efa += m * ev[0]; efb += m * ev[1];
                    xja += m * __uint_as_float(pu << 16);
                    xjb += m * __uint_as_float(pu & 0xFFFF0000u);
                }
            }
            float dgf = (float)dg;
            float inv = 1.0f / (dgf + 1e-6f);
            unsigned pk = f2bf(efa * inv) | (f2bf(efb * inv) << 16);
            unsigned byte = (unsigned)(r * 512 + 256 + lane * 4) ^ ((unsigned)(r & 7) << 4);
            *reinterpret_cast<unsigned*>(Asb + byte) = pk;
            *reinterpret_cast<float2*>(&XJ[r][l2]) = make_float2(xja * inv, xjb * inv);
            if (lane == 0) cf_s[r] = dgf * inv;
        }
    }
    __syncthreads();

    // ---- phase C: [X|Ae] @ BcTa^T; wave: 16 rows x 32 cols, K=256 ----
    {
        const int l15 = lane & 15, l4 = lane >> 4;
        const int h = w & 1;
        const int rrow = h * 16 + l15;
        const int n0 = (w >> 1) * 32;
        f32x4 acc0 = {0.f, 0.f, 0.f, 0.f}, acc1 = {0.f, 0.f, 0.f, 0.f};
        const unsigned rswz = (unsigned)(rrow & 7) << 4;
#pragma unroll
        for (int kk = 0; kk < 8; ++kk) {
            unsigned abyte = (unsigned)(rrow * 512 + (kk * 32 + l4 * 8) * 2) ^ rswz;
            bf16x8 a = *reinterpret_cast<const bf16x8*>(Asb + abyte);
            bf16x8 b0 = *reinterpret_cast<const bf16x8*>(
                BcTa + (size_t)(n0 + l15) * 256 + kk * 32 + l4 * 8);
            bf16x8 b1 = *reinterpret_cast<const bf16x8*>(
                BcTa + (size_t)(n0 + 16 + l15) * 256 + kk * 32 + l4 * 8);
            acc0 = __builtin_amdgcn_mfma_f32_16x16x32_bf16(a, b0, acc0, 0, 0, 0);
            acc1 = __builtin_amdgcn_mfma_f32_16x16x32_bf16(a, b1, acc1, 0, 0, 0);
        }
#pragma unroll
        for (int ng = 0; ng < 2; ++ng) {
            int col = n0 + ng * 16 + l15;
            float bx = bW[col];
            float bj = bW[128 + col] + bWe[col];
            f32x4 acc = ng ? acc1 : acc0;
#pragma unroll
            for (int j = 0; j < 4; ++j) {
                int lr = h * 16 + l4 * 4 + j;
                int row = m0 + lr;
                if (row < NN) {
                    float o = acc[j] + XJ[lr][col] + bx + cf_s[lr] * bj;
                    __builtin_nontemporal_store(o, &out[(size_t)row * DF + col]);
                }
            }
        }
    }
}

extern "C" void kernel_launch(void* const* d_in, const int* in_sizes, int n_in,
                              void* d_out, int out_size, void* d_ws, size_t ws_size,
                              hipStream_t stream) {
    const float* X   = (const float*)d_in[0];
    const int*   snd = (const int*)d_in[1];
    const int*   rcv = (const int*)d_in[2];
    const float* EF  = (const float*)d_in[3];
    const float* W   = (const float*)d_in[4];
    const float* bW  = (const float*)d_in[5];
    const float* We  = (const float*)d_in[6];
    const float* bWe = (const float*)d_in[7];
    float* out = (float*)d_out;

    char* ws = (char*)d_ws;
    unsigned* deg  = (unsigned*)(ws + OFF_DEG);
    unsigned* offs = (unsigned*)(ws + OFF_OFFS);
    unsigned* part = (unsigned*)(ws + OFF_PART);
    unsigned* rank = (unsigned*)(ws + OFF_RANK);
    int2*     csr  = (int2*)(ws + OFF_CSR);
    unsigned short* BcTa = (unsigned short*)(ws + OFF_BCTA);
    unsigned short* W2T  = (unsigned short*)(ws + OFF_W2T);
    unsigned short* P2   = (unsigned short*)(ws + OFF_P2);

    k_setup<<<(NN + 255) / 256, 256, 0, stream>>>(W, We, deg, BcTa, W2T);
    k_gemm1hist<<<GB + HB, 256, 0, stream>>>(X, W2T, P2, rcv, deg, rank);

    {
        const unsigned* deg_c = deg;
        const int* snd_c = snd;
        const int* rcv_c = rcv;
        const unsigned* rank_c = rank;
        void* args[] = {(void*)&deg_c, (void*)&part, (void*)&offs,
                        (void*)&snd_c, (void*)&rcv_c, (void*)&rank_c, (void*)&csr};
        hipLaunchCooperativeKernel((void*)k_csr, dim3(COOP_B), dim3(256),
                                   args, 0, stream);
    }

    k_aggemm<<<NB, 512, 0, stream>>>(X, EF, P2, offs, csr, BcTa, bW, bWe, out);
}

// Round 14
// 192.206 us; speedup vs baseline: 2.1989x; 2.1989x over previous
//
#include <hip/hip_runtime.h>

#define NN 50000
#define NE 800000
#define DF 128
#define BM 32
#define NB ((NN + BM - 1) / BM)   // 1563
#define SCAN_B ((NN + 255) / 256) // 196
#define GB ((NN + 63) / 64)       // 782 gemm blocks
#define HB ((NE + 255) / 256)     // 3125 hist blocks

typedef __attribute__((ext_vector_type(8))) short bf16x8;
typedef __attribute__((ext_vector_type(4))) float f32x4;
typedef __attribute__((ext_vector_type(2))) float f32x2;

// ---- workspace layout (bytes) ----
static const size_t OFF_DEG  = 0;         // u32[NN]
static const size_t OFF_OFFS = 204800;    // u32[NN+1]
static const size_t OFF_PART = 409600;    // u32[SCAN_B]
static const size_t OFF_RANK = 614400;    // u32[NE]
static const size_t OFF_CSR  = 3814400;   // int2[NE]
static const size_t OFF_BCTA = 10214400;  // bf16[128][256]: [col][k], k<128=W1, k>=128=We
static const size_t OFF_W2T  = 10279936;  // bf16[128][128]: [col][k] = W[k][128+col]
static const size_t OFF_P2   = 10312704;  // bf16[NN][128] = bf16(X@W[:,128:])
// total ~23.1 MB

__device__ __forceinline__ unsigned f2bf(float f) {
    unsigned u = __float_as_uint(f);
    return (u + 0x7FFFu + ((u >> 16) & 1u)) >> 16;
}
// non-temporal: EF rows are touched exactly once -> keep the 410MB stream
// from evicting the P2 gather table.
__device__ __forceinline__ f32x2 ntload2(const float* p) {
    return __builtin_nontemporal_load(reinterpret_cast<const f32x2*>(p));
}

// 32B csr block (4 edges), 8B-aligned; wave-uniform address -> scalar block load
struct __attribute__((aligned(8))) CsrBlk { int2 e[4]; };

// zero deg + build BcTa (concat [W1; We] transposed) + W2T
__global__ void k_setup(const float* __restrict__ W, const float* __restrict__ We,
                        unsigned* __restrict__ deg, unsigned short* __restrict__ BcTa,
                        unsigned short* __restrict__ W2T) {
    int idx = blockIdx.x * blockDim.x + threadIdx.x;
    if (idx < NN) deg[idx] = 0;
    if (idx < 128 * 256) {
        int col = idx >> 8, k = idx & 255;
        float v = (k < 128) ? W[k * 256 + col] : We[(k - 128) * 128 + col];
        BcTa[idx] = (unsigned short)f2bf(v);
    }
    if (idx < 128 * 128) {
        int col = idx >> 7, k = idx & 127;
        W2T[idx] = (unsigned short)f2bf(W[k * 256 + 128 + col]);
    }
}

// blocks [0,GB): P2 = bf16(X@W[:,128:]); blocks [GB,GB+HB): degree hist + rank
__global__ __launch_bounds__(256) void k_gemm1hist(
    const float* __restrict__ X, const unsigned short* __restrict__ W2T,
    unsigned short* __restrict__ P2, const int* __restrict__ rcv,
    unsigned* __restrict__ deg, unsigned* __restrict__ rank) {
    __shared__ unsigned short As[64 * 128];  // 16 KiB, XOR-swizzled
    if (blockIdx.x >= GB) {
        int e = (blockIdx.x - GB) * 256 + threadIdx.x;
        if (e < NE) rank[e] = atomicAdd(&deg[rcv[e]], 1u);
        return;
    }
    const int tid = threadIdx.x;
    const int w = tid >> 6, lane = tid & 63;
    const int l15 = lane & 15, l4 = lane >> 4;
    const int m0 = blockIdx.x * 64;
    char* Asb = (char*)As;

    for (int i = tid; i < 64 * 32; i += 256) {
        int r = i >> 5, g = i & 31;
        int n = m0 + r;
        f32x4 v = {0.f, 0.f, 0.f, 0.f};
        if (n < NN) v = *reinterpret_cast<const f32x4*>(X + (size_t)n * DF + g * 4);
        unsigned pk0 = f2bf(v[0]) | (f2bf(v[1]) << 16);
        unsigned pk1 = f2bf(v[2]) | (f2bf(v[3]) << 16);
        unsigned byte = (unsigned)(r * 256 + g * 8) ^ ((unsigned)(r & 7) << 4);
        *reinterpret_cast<uint2*>(Asb + byte) = make_uint2(pk0, pk1);
    }
    __syncthreads();

    const int rrow = w * 16 + l15;
    const unsigned rswz = (unsigned)(rrow & 7) << 4;
    f32x4 acc[8];
#pragma unroll
    for (int ng = 0; ng < 8; ++ng) acc[ng] = (f32x4){0.f, 0.f, 0.f, 0.f};
#pragma unroll
    for (int kk = 0; kk < 4; ++kk) {
        unsigned abyte = (unsigned)(rrow * 256 + (kk * 32 + l4 * 8) * 2) ^ rswz;
        bf16x8 a = *reinterpret_cast<const bf16x8*>(Asb + abyte);
#pragma unroll
        for (int ng = 0; ng < 8; ++ng) {
            bf16x8 b = *reinterpret_cast<const bf16x8*>(
                W2T + (size_t)(ng * 16 + l15) * 128 + kk * 32 + l4 * 8);
            acc[ng] = __builtin_amdgcn_mfma_f32_16x16x32_bf16(a, b, acc[ng], 0, 0, 0);
        }
    }
#pragma unroll
    for (int ng = 0; ng < 8; ++ng) {
        int col = ng * 16 + l15;
#pragma unroll
        for (int j = 0; j < 4; ++j) {
            int row = m0 + w * 16 + l4 * 4 + j;
            if (row < NN) P2[(size_t)row * DF + col] = (unsigned short)f2bf(acc[ng][j]);
        }
    }
}

__global__ void k_scan1(const unsigned* __restrict__ deg, unsigned* __restrict__ part) {
    int idx = blockIdx.x * 256 + threadIdx.x;
    unsigned v = (idx < NN) ? deg[idx] : 0;
#pragma unroll
    for (int o = 32; o; o >>= 1) v += __shfl_down(v, o);
    __shared__ unsigned wsum[4];
    int w = threadIdx.x >> 6, lane = threadIdx.x & 63;
    if (lane == 0) wsum[w] = v;
    __syncthreads();
    if (threadIdx.x == 0) part[blockIdx.x] = wsum[0] + wsum[1] + wsum[2] + wsum[3];
}

// scan3 computes its own base from part[] (wave 0) + intra-block scan
__global__ void k_scan3(const unsigned* __restrict__ deg, const unsigned* __restrict__ part,
                        unsigned* __restrict__ offs) {
    const int b = blockIdx.x;
    int idx = b * 256 + threadIdx.x;
    unsigned v = (idx < NN) ? deg[idx] : 0;
    int w = threadIdx.x >> 6, lane = threadIdx.x & 63;
    unsigned x = v;
#pragma unroll
    for (int o = 1; o < 64; o <<= 1) {
        unsigned y = __shfl_up(x, o);
        if (lane >= o) x += y;
    }
    __shared__ unsigned wsum[4];
    __shared__ unsigned base_s;
    if (lane == 63) wsum[w] = x;
    if (w == 0) {
        unsigned s = 0;
        for (int i = lane; i < b; i += 64) s += part[i];
#pragma unroll
        for (int o = 32; o; o >>= 1) s += __shfl_down(s, o);
        if (lane == 0) base_s = s;
    }
    __syncthreads();
    unsigned base = base_s;
    for (int i = 0; i < w; ++i) base += wsum[i];
    if (idx < NN) offs[idx] = base + x - v;
    if (b == SCAN_B - 1 && threadIdx.x == 255) offs[NN] = base + x;
}

__global__ void k_scatter(const int* __restrict__ snd, const int* __restrict__ rcv,
                          const unsigned* __restrict__ offs, const unsigned* __restrict__ rank,
                          int2* __restrict__ csr) {
    int e = blockIdx.x * blockDim.x + threadIdx.x;
    if (e >= NE) return;
    csr[offs[rcv[e]] + rank[e]] = make_int2(snd[e], e);
}

// fused: per 32-node tile, stage X (bf16) into A-tile cols 0..127, aggregate
// EF->Ae (A-tile cols 128..255) and P2->XJ, then one K=256 MFMA pass:
// out = [X|Ae]@[W1;We] + XJ + biases.
// phase A: whole wave per edge; csr read as 32B uniform blocks (scalar dwordx8);
// masked edges redirected to the body's first (always-valid) entry.
__global__ __launch_bounds__(512) void k_aggemm(
    const float* __restrict__ X, const float* __restrict__ EF,
    const unsigned short* __restrict__ P2, const unsigned* __restrict__ offs,
    const int2* __restrict__ csr, const unsigned short* __restrict__ BcTa,
    const float* __restrict__ bW, const float* __restrict__ bWe,
    float* __restrict__ out) {
    __shared__ unsigned short As[BM * 256];  // 16 KiB [32][256], XOR-swizzled
    __shared__ float XJ[BM][132];            // padded stride: conflict-free epilogue
    __shared__ float cf_s[BM];
    const int tid = threadIdx.x;
    const int w = tid >> 6, lane = tid & 63;
    const int m0 = blockIdx.x * BM;
    char* Asb = (char*)As;

    // ---- phase B first (independent bulk loads prefetch under phase A) ----
    for (int i = tid; i < BM * 32; i += 512) {
        int r = i >> 5, g = i & 31;
        int n = m0 + r;
        f32x4 v = {0.f, 0.f, 0.f, 0.f};
        if (n < NN) v = *reinterpret_cast<const f32x4*>(X + (size_t)n * DF + g * 4);
        unsigned pk0 = f2bf(v[0]) | (f2bf(v[1]) << 16);
        unsigned pk1 = f2bf(v[2]) | (f2bf(v[3]) << 16);
        unsigned byte = (unsigned)(r * 512 + g * 8) ^ ((unsigned)(r & 7) << 4);
        *reinterpret_cast<uint2*>(Asb + byte) = make_uint2(pk0, pk1);
    }

    // ---- phase A: wave owns 4 nodes; whole wave per edge ----
    {
        const int l2 = lane * 2;
        for (int t = 0; t < 4; ++t) {
            int r = w * 4 + t;
            int n = m0 + r;
            unsigned s0 = 0, s1 = 0;
            if (n < NN) { s0 = offs[n]; s1 = offs[n + 1]; }
            s0 = __builtin_amdgcn_readfirstlane(s0);
            s1 = __builtin_amdgcn_readfirstlane(s1);
            unsigned dg = s1 - s0;
            float efa = 0.f, efb = 0.f, xja = 0.f, xjb = 0.f;
            unsigned nb = (dg + 7) >> 3;  // 8-edge bodies, masked tail
            unsigned p = s0;
            for (unsigned bdy = 0; bdy < nb; ++bdy, p += 8) {
                // uniform 32B block loads (over-read past s1 stays inside ws;
                // masked entries are value-redirected below)
                CsrBlk bA = *reinterpret_cast<const CsrBlk*>(csr + p);
                CsrBlk bB = *reinterpret_cast<const CsrBlk*>(csr + p + 4);
                int2 safe = bA.e[0];  // p < s1 always holds for body start
#pragma unroll
                for (int i = 0; i < 8; ++i) {
                    bool act = p + i < s1;
                    int2 se = (i < 4) ? bA.e[i] : bB.e[i - 4];
                    se = act ? se : safe;  // uniform cselect
                    f32x2 ev = ntload2(EF + (size_t)se.y * DF + l2);
                    unsigned pu = *reinterpret_cast<const unsigned*>(
                        P2 + (size_t)se.x * DF + l2);
                    float m = act ? 1.f : 0.f;
                    efa += m * ev[0]; efb += m * ev[1];
                    xja += m * __uint_as_float(pu << 16);
                    xjb += m * __uint_as_float(pu & 0xFFFF0000u);
                }
            }
            float dgf = (float)dg;
            float inv = 1.0f / (dgf + 1e-6f);
            unsigned pk = f2bf(efa * inv) | (f2bf(efb * inv) << 16);
            unsigned byte = (unsigned)(r * 512 + 256 + lane * 4) ^ ((unsigned)(r & 7) << 4);
            *reinterpret_cast<unsigned*>(Asb + byte) = pk;
            *reinterpret_cast<float2*>(&XJ[r][l2]) = make_float2(xja * inv, xjb * inv);
            if (lane == 0) cf_s[r] = dgf * inv;
        }
    }
    __syncthreads();

    // ---- phase C: [X|Ae] @ BcTa^T; wave: 16 rows x 32 cols, K=256 ----
    {
        const int l15 = lane & 15, l4 = lane >> 4;
        const int h = w & 1;
        const int rrow = h * 16 + l15;
        const int n0 = (w >> 1) * 32;
        f32x4 acc0 = {0.f, 0.f, 0.f, 0.f}, acc1 = {0.f, 0.f, 0.f, 0.f};
        const unsigned rswz = (unsigned)(rrow & 7) << 4;
#pragma unroll
        for (int kk = 0; kk < 8; ++kk) {
            unsigned abyte = (unsigned)(rrow * 512 + (kk * 32 + l4 * 8) * 2) ^ rswz;
            bf16x8 a = *reinterpret_cast<const bf16x8*>(Asb + abyte);
            bf16x8 b0 = *reinterpret_cast<const bf16x8*>(
                BcTa + (size_t)(n0 + l15) * 256 + kk * 32 + l4 * 8);
            bf16x8 b1 = *reinterpret_cast<const bf16x8*>(
                BcTa + (size_t)(n0 + 16 + l15) * 256 + kk * 32 + l4 * 8);
            acc0 = __builtin_amdgcn_mfma_f32_16x16x32_bf16(a, b0, acc0, 0, 0, 0);
            acc1 = __builtin_amdgcn_mfma_f32_16x16x32_bf16(a, b1, acc1, 0, 0, 0);
        }
#pragma unroll
        for (int ng = 0; ng < 2; ++ng) {
            int col = n0 + ng * 16 + l15;
            float bx = bW[col];
            float bj = bW[128 + col] + bWe[col];
            f32x4 acc = ng ? acc1 : acc0;
#pragma unroll
            for (int j = 0; j < 4; ++j) {
                int lr = h * 16 + l4 * 4 + j;
                int row = m0 + lr;
                if (row < NN) {
                    float o = acc[j] + XJ[lr][col] + bx + cf_s[lr] * bj;
                    __builtin_nontemporal_store(o, &out[(size_t)row * DF + col]);
                }
            }
        }
    }
}

extern "C" void kernel_launch(void* const* d_in, const int* in_sizes, int n_in,
                              void* d_out, int out_size, void* d_ws, size_t ws_size,
                              hipStream_t stream) {
    const float* X   = (const float*)d_in[0];
    const int*   snd = (const int*)d_in[1];
    const int*   rcv = (const int*)d_in[2];
    const float* EF  = (const float*)d_in[3];
    const float* W   = (const float*)d_in[4];
    const float* bW  = (const float*)d_in[5];
    const float* We  = (const float*)d_in[6];
    const float* bWe = (const float*)d_in[7];
    float* out = (float*)d_out;

    char* ws = (char*)d_ws;
    unsigned* deg  = (unsigned*)(ws + OFF_DEG);
    unsigned* offs = (unsigned*)(ws + OFF_OFFS);
    unsigned* part = (unsigned*)(ws + OFF_PART);
    unsigned* rank = (unsigned*)(ws + OFF_RANK);
    int2*     csr  = (int2*)(ws + OFF_CSR);
    unsigned short* BcTa = (unsigned short*)(ws + OFF_BCTA);
    unsigned short* W2T  = (unsigned short*)(ws + OFF_W2T);
    unsigned short* P2   = (unsigned short*)(ws + OFF_P2);

    k_setup<<<(NN + 255) / 256, 256, 0, stream>>>(W, We, deg, BcTa, W2T);
    k_gemm1hist<<<GB + HB, 256, 0, stream>>>(X, W2T, P2, rcv, deg, rank);
    k_scan1<<<SCAN_B, 256, 0, stream>>>(deg, part);
    k_scan3<<<SCAN_B, 256, 0, stream>>>(deg, part, offs);
    k_scatter<<<(NE + 255) / 256, 256, 0, stream>>>(snd, rcv, offs, rank, csr);
    k_aggemm<<<NB, 512, 0, stream>>>(X, EF, P2, offs, csr, BcTa, bW, bWe, out);
}